// Round 3
// baseline (487.613 us; speedup 1.0000x reference)
//
#include <hip/hip_runtime.h>
#include <math.h>

// NeuralTPP: B=4096 sequences, L=512 steps, H=HH=32.
// Lane i of each 32-lane group owns hidden unit i; 2 batch elems per wave64.
// Weights pinned in VGPRs via empty asm (defeats rematerialization-reload).
// h broadcast via single-instruction ds_swizzle (BitMode, imm offset).
// LL transcendentals deferred to a phase-2 pass over an LDS buffer.

constexpr int Bn = 4096;
constexpr int Ln = 512;
constexpr int Hn = 32;
constexpr float EPSf = 1e-8f;

__device__ __forceinline__ float sigmoidf_(float x) {
    return __fdividef(1.0f, 1.0f + __expf(-x));
}
__device__ __forceinline__ float tanhf_(float x) {
    x = fminf(x, 15.0f);
    const float e = __expf(2.0f * x);
    return __fdividef(e - 1.0f, e + 1.0f);
}
__device__ __forceinline__ float softplusf_(float x) {
    return fmaxf(x, 0.0f) + __logf(1.0f + __expf(-fabsf(x)));
}

template <int IMM>
__device__ __forceinline__ float swz(float v) {
    return __int_as_float(__builtin_amdgcn_ds_swizzle(__float_as_int(v), IMM));
}

__global__ __launch_bounds__(256, 2)
void tpp_main(const float* __restrict__ deltas,
              const float* __restrict__ mask,
              const float* __restrict__ w_ih,
              const float* __restrict__ w_hh,
              const float* __restrict__ b_ih,
              const float* __restrict__ b_hh,
              const float* __restrict__ w1,
              const float* __restrict__ b1,
              const float* __restrict__ w2,
              const float* __restrict__ b2,
              float* __restrict__ partials)   // [2 * gridDim.x]
{
    const int tid = threadIdx.x;
    const int grp = tid >> 5;            // 0..7
    const int i   = tid & 31;            // hidden unit
    const int b   = blockIdx.x * 8 + grp;

    __shared__ float buf[8 * Ln * 2];    // [grp][t][{raw,v2}] = 32 KiB

    // ---- weights -> registers, pinned ----
    float whr[32], whz[32], whn[32], w1h[32];
    const float* pr = w_hh + (size_t)i * Hn;
    const float* pz = w_hh + (size_t)(Hn + i) * Hn;
    const float* pn = w_hh + (size_t)(2 * Hn + i) * Hn;
    const float* p1 = w1 + (size_t)i * (Hn + 1);
#pragma unroll
    for (int j = 0; j < 32; ++j) {
        whr[j] = pr[j];
        whz[j] = pz[j];
        whn[j] = pn[j];
        w1h[j] = p1[1 + j];
    }
    // Pin: make each value the result of an opaque asm so the compiler cannot
    // rematerialize the global load inside the loop; it must keep a VGPR.
#pragma unroll
    for (int j = 0; j < 32; ++j) {
        asm volatile("" : "+v"(whr[j]), "+v"(whz[j]), "+v"(whn[j]), "+v"(w1h[j]));
    }

    const float wihr = w_ih[i], wihz = w_ih[Hn + i], wihn = w_ih[2 * Hn + i];
    const float bihn = b_ih[2 * Hn + i];
    const float br = b_ih[i] + b_hh[i];            // merged r biases
    const float bz = b_ih[Hn + i] + b_hh[Hn + i];  // merged z biases
    const float bhn = b_hh[2 * Hn + i];            // n-gate hh bias
    const float w1t = p1[0];
    const float b1i = b1[i];
    const float w2i = w2[i];
    const float ci  = w1t * w2i;
    const float b2v = b2[0];

    const float* dp = deltas + (size_t)b * Ln;
    const float* mp = mask   + (size_t)b * Ln;

    float h = 0.0f;
    float tau = dp[0];
    float m   = mp[0];

    for (int t = 0; t < Ln; ++t) {
        const int tn = (t + 1 < Ln) ? (t + 1) : (Ln - 1);
        const float tau_n = dp[tn];
        const float m_n   = mp[tn];

        float hr = br, hz = bz, hn = bhn;
        float pre = fmaf(tau, w1t, b1i);

        // h broadcast: one ds_swizzle per j (BitMode and=0, or=j)
#define BCJ(J) { const float hj = swz<((J) << 5)>(h);            \
                 hr  = fmaf(whr[J], hj, hr);                     \
                 hz  = fmaf(whz[J], hj, hz);                     \
                 hn  = fmaf(whn[J], hj, hn);                     \
                 pre = fmaf(w1h[J], hj, pre); }
        BCJ(0)  BCJ(1)  BCJ(2)  BCJ(3)  BCJ(4)  BCJ(5)  BCJ(6)  BCJ(7)
        BCJ(8)  BCJ(9)  BCJ(10) BCJ(11) BCJ(12) BCJ(13) BCJ(14) BCJ(15)
        BCJ(16) BCJ(17) BCJ(18) BCJ(19) BCJ(20) BCJ(21) BCJ(22) BCJ(23)
        BCJ(24) BCJ(25) BCJ(26) BCJ(27) BCJ(28) BCJ(29) BCJ(30) BCJ(31)
#undef BCJ

        // ---- intensity scalars; fused dual reduction ----
        const float a  = tanhf_(pre);
        float v1 = a * w2i;
        float v2 = fmaf(a * a, -ci, ci);       // (1-a^2)*w1t*w2
        // level 1: exchange with lane^1, even lanes keep v1-sum, odd keep v2-sum
        const float t1 = swz<((1 << 10) | 0x1f)>(v1);
        const float t2 = swz<((1 << 10) | 0x1f)>(v2);
        float s = (i & 1) ? (v2 + t2) : (v1 + t1);
        // levels 2..5 reduce both sums simultaneously
        s += swz<((2 << 10) | 0x1f)>(s);
        s += swz<((4 << 10) | 0x1f)>(s);
        s += swz<((8 << 10) | 0x1f)>(s);
        s += swz<((16 << 10) | 0x1f)>(s);
        // lane 0: sum(v1) -> raw (minus b2), lane 1: sum(v2)
        if (i < 2) buf[(grp << 10) + (t << 1) + i] = (i == 0) ? (s + b2v) : s;

        // ---- GRU update ----
        const float r  = sigmoidf_(fmaf(tau, wihr, hr));
        const float z  = sigmoidf_(fmaf(tau, wihz, hz));
        const float n  = tanhf_(fmaf(r, hn, fmaf(tau, wihn, bihn)));
        const float nh = fmaf(1.0f - z, n, z * h);
        h = fmaf(m, nh - h, h);

        tau = tau_n;
        m   = m_n;
    }

    __syncthreads();

    // ---- phase 2: LL transcendentals, all 256 lanes useful ----
    const float* mblk = mask + (size_t)blockIdx.x * 8 * Ln;
    float T = 0.0f, M = 0.0f;
#pragma unroll
    for (int k = 0; k < 16; ++k) {
        const int idx = (k << 8) + tid;            // 0..4095 over [grp][t]
        const float raw = buf[idx * 2];
        const float v2  = buf[idx * 2 + 1];
        const float mm  = mblk[idx];
        const float phi  = softplusf_(raw);
        const float dphi = sigmoidf_(raw) * v2;
        const float lam  = softplusf_(dphi) + EPSf;
        T = fmaf(__logf(lam) - phi, mm, T);
        M += mm;
    }
#pragma unroll
    for (int d = 1; d < 64; d <<= 1) {
        T += __shfl_xor(T, d, 64);
        M += __shfl_xor(M, d, 64);
    }
    __shared__ float sT[4], sM[4];
    const int w = tid >> 6;
    if ((tid & 63) == 0) { sT[w] = T; sM[w] = M; }
    __syncthreads();
    if (tid == 0) {
        partials[blockIdx.x]             = sT[0] + sT[1] + sT[2] + sT[3];
        partials[gridDim.x + blockIdx.x] = sM[0] + sM[1] + sM[2] + sM[3];
    }
}

__global__ __launch_bounds__(256)
void tpp_final(const float* __restrict__ partials, int nparts,
               float* __restrict__ out)
{
    const int tid = threadIdx.x;
    double T = 0.0, M = 0.0;
    for (int k = tid; k < nparts; k += 256) {
        T += (double)partials[k];
        M += (double)partials[nparts + k];
    }
#pragma unroll
    for (int d = 1; d < 64; d <<= 1) {
        T += __shfl_xor(T, d, 64);
        M += __shfl_xor(M, d, 64);
    }
    __shared__ double sT[4], sM[4];
    const int w = tid >> 6;
    if ((tid & 63) == 0) { sT[w] = T; sM[w] = M; }
    __syncthreads();
    if (tid == 0) {
        const double t2 = sT[0] + sT[1] + sT[2] + sT[3];
        const double m2 = sM[0] + sM[1] + sM[2] + sM[3];
        out[0] = (float)(t2 / (m2 + (double)EPSf));
    }
}

extern "C" void kernel_launch(void* const* d_in, const int* in_sizes, int n_in,
                              void* d_out, int out_size, void* d_ws, size_t ws_size,
                              hipStream_t stream) {
    const float* deltas = (const float*)d_in[0];
    const float* mask   = (const float*)d_in[1];
    const float* w_ih   = (const float*)d_in[2];
    const float* w_hh   = (const float*)d_in[3];
    const float* b_ih   = (const float*)d_in[4];
    const float* b_hh   = (const float*)d_in[5];
    const float* w1     = (const float*)d_in[6];
    const float* b1     = (const float*)d_in[7];
    const float* w2     = (const float*)d_in[8];
    const float* b2     = (const float*)d_in[9];
    float* out = (float*)d_out;
    float* partials = (float*)d_ws;     // 2 * 512 * 4 B = 4 KiB

    const int nblocks = Bn / 8;         // 512
    tpp_main<<<nblocks, 256, 0, stream>>>(deltas, mask, w_ih, w_hh, b_ih, b_hh,
                                          w1, b1, w2, b2, partials);
    tpp_final<<<1, 256, 0, stream>>>(partials, nblocks, out);
}

// Round 4
// 484.699 us; speedup vs baseline: 1.0060x; 1.0060x over previous
//
#include <hip/hip_runtime.h>
#include <math.h>

// NeuralTPP: B=4096 sequences, L=512 steps, H=HH=32.
// Lane i of each 32-lane group owns hidden unit i; 2 batch elems per wave64.
// Weights live in LDS, TRANSPOSED and packed as float2, read in the unrolled
// j-loop as ds_read_b64 with one base VGPR + immediate offsets (no per-step
// address math, no VMEM). h broadcast via single-instruction ds_swizzle.
// LL transcendentals deferred to a phase-2 pass over an LDS buffer.

constexpr int Bn = 4096;
constexpr int Ln = 512;
constexpr int Hn = 32;
constexpr float EPSf = 1e-8f;

__device__ __forceinline__ float sigmoidf_(float x) {
    return __fdividef(1.0f, 1.0f + __expf(-x));
}
__device__ __forceinline__ float tanhf_(float x) {
    x = fminf(x, 15.0f);
    const float e = __expf(2.0f * x);
    return __fdividef(e - 1.0f, e + 1.0f);
}
__device__ __forceinline__ float softplusf_(float x) {
    return fmaxf(x, 0.0f) + __logf(1.0f + __expf(-fabsf(x)));
}

template <int IMM>
__device__ __forceinline__ float swz(float v) {
    return __int_as_float(__builtin_amdgcn_ds_swizzle(__float_as_int(v), IMM));
}

__global__ __launch_bounds__(256, 2)
void tpp_main(const float* __restrict__ deltas,
              const float* __restrict__ mask,
              const float* __restrict__ w_ih,
              const float* __restrict__ w_hh,
              const float* __restrict__ b_ih,
              const float* __restrict__ b_hh,
              const float* __restrict__ w1,
              const float* __restrict__ b1,
              const float* __restrict__ w2,
              const float* __restrict__ b2,
              float* __restrict__ partials)   // [2 * gridDim.x]
{
    const int tid = threadIdx.x;
    const int grp = tid >> 5;            // 0..7
    const int i   = tid & 31;            // hidden unit
    const int b   = blockIdx.x * 8 + grp;

    // LDS: transposed weight pairs + deferred-transcendental buffer
    __shared__ float2 wpk0[Hn][Hn];      // [j][i] = (whr[i][j], whz[i][j])  8 KiB
    __shared__ float2 wpk1[Hn][Hn];      // [j][i] = (whn[i][j], w1h[i][j])  8 KiB
    __shared__ float  buf[8 * Ln * 2];   // [grp][t][{raw,v2}]              32 KiB

    // ---- stage weights into LDS (transpose on the fly), once ----
    for (int k = tid; k < Hn * Hn; k += 256) {
        const int j = k >> 5, ii = k & 31;
        wpk0[j][ii] = make_float2(w_hh[ii * Hn + j],        w_hh[(Hn + ii) * Hn + j]);
        wpk1[j][ii] = make_float2(w_hh[(2 * Hn + ii) * Hn + j], w1[ii * (Hn + 1) + 1 + j]);
    }

    const float wihr = w_ih[i], wihz = w_ih[Hn + i], wihn = w_ih[2 * Hn + i];
    const float bihn = b_ih[2 * Hn + i];
    const float br = b_ih[i] + b_hh[i];            // merged r biases
    const float bz = b_ih[Hn + i] + b_hh[Hn + i];  // merged z biases
    const float bhn = b_hh[2 * Hn + i];            // n-gate hh bias
    const float w1t = w1[i * (Hn + 1)];
    const float b1i = b1[i];
    const float w2i = w2[i];
    const float ci  = w1t * w2i;
    const float b2v = b2[0];

    const float* dp = deltas + (size_t)b * Ln;
    const float* mp = mask   + (size_t)b * Ln;

    float h = 0.0f;
    float tau = dp[0];
    float m   = mp[0];

    __syncthreads();

    for (int t = 0; t < Ln; ++t) {
        const int tn = (t + 1 < Ln) ? (t + 1) : (Ln - 1);
        const float tau_n = dp[tn];
        const float m_n   = mp[tn];

        float hr = br, hz = bz, hn = bhn;
        float pre = fmaf(tau, w1t, b1i);

        // ds_swizzle broadcast of h[j] + two ds_read_b64 weight pairs per j
        // (immediate offsets; banks 2i%32 -> 2-way aliasing = free)
#define BCJ(J) { const float hj = swz<((J) << 5)>(h);            \
                 const float2 a0 = wpk0[J][i];                   \
                 const float2 a1 = wpk1[J][i];                   \
                 hr  = fmaf(a0.x, hj, hr);                       \
                 hz  = fmaf(a0.y, hj, hz);                       \
                 hn  = fmaf(a1.x, hj, hn);                       \
                 pre = fmaf(a1.y, hj, pre); }
        BCJ(0)  BCJ(1)  BCJ(2)  BCJ(3)  BCJ(4)  BCJ(5)  BCJ(6)  BCJ(7)
        BCJ(8)  BCJ(9)  BCJ(10) BCJ(11) BCJ(12) BCJ(13) BCJ(14) BCJ(15)
        BCJ(16) BCJ(17) BCJ(18) BCJ(19) BCJ(20) BCJ(21) BCJ(22) BCJ(23)
        BCJ(24) BCJ(25) BCJ(26) BCJ(27) BCJ(28) BCJ(29) BCJ(30) BCJ(31)
#undef BCJ

        // ---- intensity scalars; fused dual reduction ----
        const float a  = tanhf_(pre);
        float v1 = a * w2i;
        float v2 = fmaf(a * a, -ci, ci);       // (1-a^2)*w1t*w2
        const float t1 = swz<((1 << 10) | 0x1f)>(v1);
        const float t2 = swz<((1 << 10) | 0x1f)>(v2);
        float s = (i & 1) ? (v2 + t2) : (v1 + t1);
        s += swz<((2 << 10) | 0x1f)>(s);
        s += swz<((4 << 10) | 0x1f)>(s);
        s += swz<((8 << 10) | 0x1f)>(s);
        s += swz<((16 << 10) | 0x1f)>(s);
        if (i < 2) buf[(grp << 10) + (t << 1) + i] = (i == 0) ? (s + b2v) : s;

        // ---- GRU update ----
        const float r  = sigmoidf_(fmaf(tau, wihr, hr));
        const float z  = sigmoidf_(fmaf(tau, wihz, hz));
        const float n  = tanhf_(fmaf(r, hn, fmaf(tau, wihn, bihn)));
        const float nh = fmaf(1.0f - z, n, z * h);
        h = fmaf(m, nh - h, h);

        tau = tau_n;
        m   = m_n;
    }

    __syncthreads();

    // ---- phase 2: LL transcendentals, all 256 lanes useful ----
    const float* mblk = mask + (size_t)blockIdx.x * 8 * Ln;
    float T = 0.0f, M = 0.0f;
#pragma unroll
    for (int k = 0; k < 16; ++k) {
        const int idx = (k << 8) + tid;            // 0..4095 over [grp][t]
        const float raw = buf[idx * 2];
        const float v2  = buf[idx * 2 + 1];
        const float mm  = mblk[idx];
        const float phi  = softplusf_(raw);
        const float dphi = sigmoidf_(raw) * v2;
        const float lam  = softplusf_(dphi) + EPSf;
        T = fmaf(__logf(lam) - phi, mm, T);
        M += mm;
    }
#pragma unroll
    for (int d = 1; d < 64; d <<= 1) {
        T += __shfl_xor(T, d, 64);
        M += __shfl_xor(M, d, 64);
    }
    __shared__ float sT[4], sM[4];
    const int w = tid >> 6;
    if ((tid & 63) == 0) { sT[w] = T; sM[w] = M; }
    __syncthreads();
    if (tid == 0) {
        partials[blockIdx.x]             = sT[0] + sT[1] + sT[2] + sT[3];
        partials[gridDim.x + blockIdx.x] = sM[0] + sM[1] + sM[2] + sM[3];
    }
}

__global__ __launch_bounds__(256)
void tpp_final(const float* __restrict__ partials, int nparts,
               float* __restrict__ out)
{
    const int tid = threadIdx.x;
    double T = 0.0, M = 0.0;
    for (int k = tid; k < nparts; k += 256) {
        T += (double)partials[k];
        M += (double)partials[nparts + k];
    }
#pragma unroll
    for (int d = 1; d < 64; d <<= 1) {
        T += __shfl_xor(T, d, 64);
        M += __shfl_xor(M, d, 64);
    }
    __shared__ double sT[4], sM[4];
    const int w = tid >> 6;
    if ((tid & 63) == 0) { sT[w] = T; sM[w] = M; }
    __syncthreads();
    if (tid == 0) {
        const double t2 = sT[0] + sT[1] + sT[2] + sT[3];
        const double m2 = sM[0] + sM[1] + sM[2] + sM[3];
        out[0] = (float)(t2 / (m2 + (double)EPSf));
    }
}

extern "C" void kernel_launch(void* const* d_in, const int* in_sizes, int n_in,
                              void* d_out, int out_size, void* d_ws, size_t ws_size,
                              hipStream_t stream) {
    const float* deltas = (const float*)d_in[0];
    const float* mask   = (const float*)d_in[1];
    const float* w_ih   = (const float*)d_in[2];
    const float* w_hh   = (const float*)d_in[3];
    const float* b_ih   = (const float*)d_in[4];
    const float* b_hh   = (const float*)d_in[5];
    const float* w1     = (const float*)d_in[6];
    const float* b1     = (const float*)d_in[7];
    const float* w2     = (const float*)d_in[8];
    const float* b2     = (const float*)d_in[9];
    float* out = (float*)d_out;
    float* partials = (float*)d_ws;     // 2 * 512 * 4 B = 4 KiB

    const int nblocks = Bn / 8;         // 512
    tpp_main<<<nblocks, 256, 0, stream>>>(deltas, mask, w_ih, w_hh, b_ih, b_hh,
                                          w1, b1, w2, b2, partials);
    tpp_final<<<1, 256, 0, stream>>>(partials, nblocks, out);
}